// Round 7
// baseline (210.701 us; speedup 1.0000x reference)
//
#include <hip/hip_runtime.h>
#include <math.h>

// Problem constants (fixed by setup_inputs)
#define BATCH 4
#define CCH   256   // channels
#define DQK   32    // q/k channels
#define NPIX  4096  // H*W
#define LOG2E 1.44269504088896340736f

typedef __attribute__((ext_vector_type(8)))  short          short8_t;
typedef __attribute__((ext_vector_type(4)))  unsigned short ushort4_t;
typedef __attribute__((ext_vector_type(8)))  unsigned short ushort8_t;
typedef __attribute__((ext_vector_type(16))) float          f32x16;
typedef __attribute__((ext_vector_type(2)))  unsigned int   uint2_t;

#if __has_builtin(__builtin_amdgcn_exp2f)
#define EXP2F(x) __builtin_amdgcn_exp2f(x)
#else
#define EXP2F(x) exp2f(x)
#endif

#define MFMA32(a, b, c) __builtin_amdgcn_mfma_f32_32x32x16_bf16(a, b, c, 0, 0, 0)

static __device__ __forceinline__ unsigned short f2bf(float f) {
    union { float f; unsigned int u; } v; v.f = f;
    unsigned int r = v.u + 0x7FFFu + ((v.u >> 16) & 1u);   // RNE
    return (unsigned short)(r >> 16);
}

static __device__ __forceinline__ short8_t cat8(ushort4_t a, ushort4_t b) {
    ushort8_t c = __builtin_shufflevector(a, b, 0, 1, 2, 3, 4, 5, 6, 7);
    short8_t r; __builtin_memcpy(&r, &c, 16); return r;
}

static __device__ __forceinline__ short8_t u4_to_s8(const unsigned int* u) {
    short8_t r; __builtin_memcpy(&r, u, 16); return r;
}

// permlane32_swap(a,b) -> {x = {a_lo32lanes, b_lo32lanes}, y = {a_hi, b_hi}}
static __device__ __forceinline__ uint2_t plswap(unsigned int a, unsigned int b) {
#if __has_builtin(__builtin_amdgcn_permlane32_swap)
    return __builtin_amdgcn_permlane32_swap(a, b, false, false);
#else
    const unsigned int sa = (unsigned int)__shfl_xor((int)a, 32);
    const unsigned int sb = (unsigned int)__shfl_xor((int)b, 32);
    const int h = (threadIdx.x >> 5) & 1;
    uint2_t r;
    r.x = h ? sb : a;
    r.y = h ? b : sa;
    return r;
#endif
}

// S (C-layout) -> exp2 -> packed bf16 PV B-operand fragments; accumulates l
static __device__ __forceinline__ void make_bfrag(
    const f32x16& s, float& l0, float& l1, unsigned int bfr[2][4])
{
    float pv[16];
    #pragma unroll
    for (int r = 0; r < 16; ++r) pv[r] = EXP2F(s[r]);
    #pragma unroll
    for (int r = 0; r < 16; r += 2) { l0 += pv[r]; l1 += pv[r + 1]; }
    unsigned int P[8];
    #pragma unroll
    for (int v = 0; v < 8; ++v)
        P[v] = __builtin_amdgcn_perm(__float_as_uint(pv[2 * v + 1]),
                                     __float_as_uint(pv[2 * v]), 0x07060302u);
    #pragma unroll
    for (int kp = 0; kp < 2; ++kp) {
        const uint2_t r02 = plswap(P[4 * kp + 0], P[4 * kp + 2]);
        const uint2_t r13 = plswap(P[4 * kp + 1], P[4 * kp + 3]);
        bfr[kp][0] = r02.x; bfr[kp][1] = r13.x;
        bfr[kp][2] = r02.y; bfr[kp][3] = r13.y;
    }
}

// ---------------------------------------------------------------------------
// Stage 0a: weights -> bf16 A-fragment layout wbf[((c>>3)*320 + o)*8 + (c&7)]
// (o: 0-31 Wq x log2e, 32-63 Wk, 64-319 Wv).
// ---------------------------------------------------------------------------
__global__ __launch_bounds__(256) void wconv_kernel(
    const float* __restrict__ Wq, const float* __restrict__ Wk,
    const float* __restrict__ Wv, unsigned short* __restrict__ wbf)
{
    const int idx = blockIdx.x * 256 + threadIdx.x;   // grid 320 -> 81920
    const int o = idx >> 8, c = idx & 255;
    float v;
    if (o < 32)      v = Wq[o * 256 + c] * LOG2E;
    else if (o < 64) v = Wk[(o - 32) * 256 + c];
    else             v = Wv[(o - 64) * 256 + c];
    wbf[((c >> 3) * 320 + o) * 8 + (c & 7)] = f2bf(v);
}

// ---------------------------------------------------------------------------
// Stage 0b: x (fp32 [b][c][n]) -> bf16 B-fragment layout
//   xfrag[(((b*128 + nt)*32 + slot)*32 + il)*8 + e],  c = slot*8+e, n = nt*32+il
// Register-only transpose: block = (b, cg in 4, ng in 16) covers 64c x 256n.
// Reads: 256B bursts; writes: dense coalesced 16B/lane runs.
// ---------------------------------------------------------------------------
__global__ __launch_bounds__(256) void xt_kernel(
    const float* __restrict__ x, unsigned short* __restrict__ xfrag)
{
    const int b  = blockIdx.x >> 6;
    const int cg = (blockIdx.x >> 4) & 3;
    const int ng = blockIdx.x & 15;
    const int t  = threadIdx.x;
    const int w = t >> 6, l = t & 63;

    #pragma unroll
    for (int sgl = 0; sgl < 2; ++sgl) {
        const int sg = w * 2 + sgl;          // block-local c-octet, 0..7
        float f[4][8];
        #pragma unroll
        for (int p = 0; p < 8; ++p) {
            const float* row = x + ((size_t)(b * CCH + cg * 64 + sg * 8 + p)) * NPIX
                                 + ng * 256;
            #pragma unroll
            for (int j = 0; j < 4; ++j)
                f[j][p] = row[j * 64 + l];
        }
        #pragma unroll
        for (int j = 0; j < 4; ++j) {
            unsigned int d[4];
            #pragma unroll
            for (int k = 0; k < 4; ++k)
                d[k] = __builtin_amdgcn_perm(__float_as_uint(f[j][2 * k + 1]),
                                             __float_as_uint(f[j][2 * k]), 0x07060302u);
            const int nt = ng * 8 + j * 2 + (l >> 5);
            unsigned short* dst = xfrag +
                ((((size_t)(b * 128 + nt) * 32) + cg * 8 + sg) * 32 + (l & 31)) * 8;
            *(short8_t*)dst = u4_to_s8(d);
        }
    }
}

// ---------------------------------------------------------------------------
// Stage 1: LDS-free MFMA projections. D[o=320][n] = W[o][c] * x[c][n].
// Block = (b, 64-n tile), grid 256, 320 thr = 5 waves (wave w: o = 64w..).
// K-loop: W A-frags + xfrag B-frags, all coalesced global loads, no barriers.
// Epilogue: per-wave LDS transpose (no barriers) into fragment layouts:
//   qfrag/kfrag[(((b*128+jt)*4 + dslot)*32 + n&31)*8]   (8 d-elems per chunk)
//   vfrag[(((b*128+jt)*4 + jslot)*256 + c)*8]           (8 j-elems per chunk)
// ---------------------------------------------------------------------------
__global__ __launch_bounds__(320) void proj_kernel(
    const unsigned short* __restrict__ xfrag, const unsigned short* __restrict__ wbf,
    const float* __restrict__ bq, const float* __restrict__ bk,
    const float* __restrict__ bv,
    unsigned short* __restrict__ qfrag, unsigned short* __restrict__ kfrag,
    unsigned short* __restrict__ vfrag)
{
    __shared__ unsigned short qkb[2 * 2 * 32 * 40];  // [it][q/k][n 32][d 32+pad]
    __shared__ unsigned short vbuf[4 * 64 * 72];     // per v-wave [c 64][n 64+pad]

    const int b   = blockIdx.x >> 6;
    const int nt0 = (blockIdx.x & 63) << 1;          // first 32-n tile of this block
    const int t   = threadIdx.x;
    const int w = t >> 6, lane = t & 63, il = lane & 31, h = lane >> 5;

    // bias prefetch (lane needs base + 8g + 4h + 0..3 for g = r>>2)
    float4 bA[4], bB[4];
    #pragma unroll
    for (int g = 0; g < 4; ++g) {
        if (w == 0) {
            bA[g] = *(const float4*)&bq[8 * g + 4 * h];
            bB[g] = *(const float4*)&bk[8 * g + 4 * h];
        } else {
            bA[g] = *(const float4*)&bv[(w - 1) * 64 + 8 * g + 4 * h];
            bB[g] = *(const float4*)&bv[(w - 1) * 64 + 32 + 8 * g + 4 * h];
        }
    }

    f32x16 acc[2][2];   // [o-half][it]
    #pragma unroll
    for (int a = 0; a < 2; ++a)
        #pragma unroll
        for (int i = 0; i < 2; ++i)
            #pragma unroll
            for (int r = 0; r < 16; ++r) acc[a][i][r] = 0.f;

    const unsigned short* wp = wbf + ((size_t)(h * 320 + w * 64 + il)) * 8;
    const unsigned short* xp0 = xfrag + (((size_t)(b * 128 + nt0) * 32 + h) * 32 + il) * 8;
    const unsigned short* xp1 = xp0 + (size_t)32 * 32 * 8;   // nt0+1

    #pragma unroll 4
    for (int ks = 0; ks < 16; ++ks) {
        const short8_t af0 = *(const short8_t*)(wp + ks * 5120);
        const short8_t af1 = *(const short8_t*)(wp + ks * 5120 + 256);
        const short8_t bf0 = *(const short8_t*)(xp0 + (size_t)ks * 2 * 256);
        const short8_t bf1 = *(const short8_t*)(xp1 + (size_t)ks * 2 * 256);
        acc[0][0] = MFMA32(af0, bf0, acc[0][0]);
        acc[0][1] = MFMA32(af0, bf1, acc[0][1]);
        acc[1][0] = MFMA32(af1, bf0, acc[1][0]);
        acc[1][1] = MFMA32(af1, bf1, acc[1][1]);
    }

    // ---- epilogue (same-wave LDS transposes only; zero barriers) ----
    if (w == 0) {
        // q = acc[0][it], k = acc[1][it].  C: col=il=n, row d = (r&3)+8*(r>>2)+4h
        #pragma unroll
        for (int it = 0; it < 2; ++it)
            #pragma unroll
            for (int r = 0; r < 16; ++r) {
                const int d = (r & 3) + 8 * (r >> 2) + 4 * h;
                qkb[(it * 2 + 0) * 1280 + il * 40 + d] =
                    f2bf(acc[0][it][r] + bA[r >> 2][r & 3] * LOG2E);
                qkb[(it * 2 + 1) * 1280 + il * 40 + d] =
                    f2bf(acc[1][it][r] + bB[r >> 2][r & 3]);
            }
        #pragma unroll
        for (int it = 0; it < 2; ++it)
            #pragma unroll
            for (int rep = 0; rep < 2; ++rep) {
                const int u = rep * 64 + lane;       // 128 chunks: slot(4) x n(32)
                const int slot = u >> 5, n = u & 31;
                ushort4_t qlo = *(const ushort4_t*)&qkb[(it * 2) * 1280 + n * 40 + slot * 8];
                ushort4_t qhi = *(const ushort4_t*)&qkb[(it * 2) * 1280 + n * 40 + slot * 8 + 4];
                ushort4_t klo = *(const ushort4_t*)&qkb[(it * 2 + 1) * 1280 + n * 40 + slot * 8];
                ushort4_t khi = *(const ushort4_t*)&qkb[(it * 2 + 1) * 1280 + n * 40 + slot * 8 + 4];
                const size_t o8 = (((size_t)(b * 128 + nt0 + it) * 4 + slot) * 32 + n) * 8;
                *(short8_t*)(qfrag + o8) = cat8(qlo, qhi);
                *(short8_t*)(kfrag + o8) = cat8(klo, khi);
            }
    } else {
        unsigned short* vb = vbuf + (w - 1) * 64 * 72;   // [c 64][n 64 pad 72]
        #pragma unroll
        for (int it = 0; it < 2; ++it)
            #pragma unroll
            for (int r = 0; r < 16; ++r) {
                const int orow = (r & 3) + 8 * (r >> 2) + 4 * h;
                vb[(orow)      * 72 + it * 32 + il] = f2bf(acc[0][it][r] + bA[r >> 2][r & 3]);
                vb[(orow + 32) * 72 + it * 32 + il] = f2bf(acc[1][it][r] + bB[r >> 2][r & 3]);
            }
        #pragma unroll
        for (int rep = 0; rep < 8; ++rep) {
            const int u = rep * 64 + lane;   // 512 chunks: (it,slot)(8) x c(64)
            const int c = u & 63, m = u >> 6;
            const int it = m >> 2, slot = m & 3;
            ushort4_t lo = *(const ushort4_t*)&vb[c * 72 + it * 32 + slot * 8];
            ushort4_t hi = *(const ushort4_t*)&vb[c * 72 + it * 32 + slot * 8 + 4];
            const size_t o8 = (((size_t)(b * 128 + nt0 + it) * 4 + slot) * 256 +
                               (w - 1) * 64 + c) * 8;
            *(short8_t*)(vfrag + o8) = cat8(lo, hi);
        }
    }
}

// ---------------------------------------------------------------------------
// Stage 2: MFMA flash attention — ZERO LDS / barriers in the main loop.
// v7: block = (b, 32-query tile), grid 512, 512 thr = 8 waves.
// Wave w -> ci = w&3 (c-QUARTER, 2 c-tiles = 64 ch), jq = w>>2 (j-half, 64
// j-tiles). Single S-chain per wave (TLP replaces ILP at 4 waves/SIMD).
// REGISTER MODEL (rounds 0-6 reconciled): per-SIMD pool = 512 regs; CSV
// VGPR_Count = ARCH only; MFMA acc lives in AGPRs counted against the same
// pool. v3/v6: 108 arch + 64 agpr = 172 -> only 2 waves/SIMD, so round-6's
// 2nd block never co-scheduled (dur 60.5 -> 75.6 = serialized half-blocks).
// launch_bounds 2nd arg = min waves/EU; budget = 512/minw TOTAL: (512,4) on
// the 172-demand wave forced 64+64 and spilled (v5). v7 shrinks the wave:
// acc[2]=32 agpr, V[2][2]=32, K dbuf 16, qf 8, transients ~30 => ~122 total
// <= 128, so __launch_bounds__(512,4) fits WITHOUT spill -> 4 waves/SIMD.
// Cost: QK/softmax 4x-redundant (VALU ~17us, MFMA ~21us totals) but both
// pipes overlap across 4 waves/SIMD -> floor ~max(21,25)us vs v3's
// latency-bound 60.5.
// p = exp2(s) un-normalized => disjoint-j partials add linearly; 2-round LDS
// combine with partner wave w^4 (other j-half, same ci).
// Grid 512, XCD-batch affinity via blk%8.
// ---------------------------------------------------------------------------
struct KStage { short8_t k0, k1; };

__global__ __launch_bounds__(512, 4) void attn_kernel(
    const unsigned short* __restrict__ qfrag,
    const unsigned short* __restrict__ kfrag,
    const unsigned short* __restrict__ vfrag,
    const float* __restrict__ x,             // [B][C][N] fp32
    const float* __restrict__ gamma,
    float* __restrict__ out)
{
    __shared__ float comb[8][64][17];        // 34.8 KB, end-combine only

    const int m8 = blockIdx.x & 7;
    const int b  = m8 >> 1;
    const int qt = ((blockIdx.x >> 3) << 1) | (m8 & 1);   // 0..127
    const int i0 = qt << 5;
    const int t  = threadIdx.x;
    const int w = t >> 6, lane = t & 63, il = lane & 31, h = lane >> 5;
    const int ci = w & 3, jq = w >> 2;       // c-quarter, j-half

    // Q fragments: chunk (nt = qt, slot = ks*2+h, il)
    short8_t qf[2];
    #pragma unroll
    for (int ks = 0; ks < 2; ++ks)
        qf[ks] = *(const short8_t*)(qfrag +
            (((size_t)(b * 128 + qt) * 4 + ks * 2 + h) * 32 + il) * 8);

    const size_t kbase = (size_t)(b * 128 + jq * 64) * 1024 + h * 256 + il * 8;
    const size_t vbase = (size_t)(b * 128 + jq * 64) * 8192 + h * 2048 +
                         (ci * 64 + il) * 8;

    f32x16 zf;
    #pragma unroll
    for (int r = 0; r < 16; ++r) zf[r] = 0.f;
    f32x16 acc[2];       // [ct]  (ct: 32-channel tiles at ci*64 + ct*32)
    acc[0] = zf; acc[1] = zf;
    float ls[2] = {0.f, 0.f};

    KStage A, B;
    short8_t va[2][2], vb[2][2];   // [ct][kp], double-buffered j-tiles

    auto loadK = [&](KStage& S, int jt) {
        const unsigned short* kp = kfrag + kbase + (size_t)jt * 1024;
        S.k0 = *(const short8_t*)kp;
        S.k1 = *(const short8_t*)(kp + 512);
    };
    auto loadV = [&](short8_t (&vv)[2][2], int jt) {
        const unsigned short* vp = vfrag + vbase + (size_t)jt * 8192;
        #pragma unroll
        for (int ct = 0; ct < 2; ++ct) {
            vv[ct][0] = *(const short8_t*)(vp + ct * 256);
            vv[ct][1] = *(const short8_t*)(vp + ct * 256 + 4096);
        }
    };

    loadK(A, 0);
    loadK(B, 1);
    loadV(va, 0);
    loadV(vb, 1);

    #pragma unroll 1
    for (int jt = 0; jt < 64; jt += 2) {
        // tile A
        f32x16 s = MFMA32(A.k0, qf[0], zf);
        s = MFMA32(A.k1, qf[1], s);
        if (jt + 2 < 64) loadK(A, jt + 2);
        unsigned int bf[2][4];
        make_bfrag(s, ls[0], ls[1], bf);
        acc[0] = MFMA32(va[0][0], u4_to_s8(bf[0]), acc[0]);
        acc[0] = MFMA32(va[0][1], u4_to_s8(bf[1]), acc[0]);
        acc[1] = MFMA32(va[1][0], u4_to_s8(bf[0]), acc[1]);
        acc[1] = MFMA32(va[1][1], u4_to_s8(bf[1]), acc[1]);
        if (jt + 2 < 64) loadV(va, jt + 2);
        // tile B
        s = MFMA32(B.k0, qf[0], zf);
        s = MFMA32(B.k1, qf[1], s);
        if (jt + 3 < 64) loadK(B, jt + 3);
        make_bfrag(s, ls[0], ls[1], bf);
        acc[0] = MFMA32(vb[0][0], u4_to_s8(bf[0]), acc[0]);
        acc[0] = MFMA32(vb[0][1], u4_to_s8(bf[1]), acc[0]);
        acc[1] = MFMA32(vb[1][0], u4_to_s8(bf[0]), acc[1]);
        acc[1] = MFMA32(vb[1][1], u4_to_s8(bf[1]), acc[1]);
        if (jt + 3 < 64) loadV(vb, jt + 3);
    }

    // ---- combine j-halves (partner wave w^4, same ci) and write out ----
    float l = ls[0] + ls[1];
    l += __shfl_xor(l, 32);                  // combine h halves of j rows
    const float gam = gamma[0];
    const int pw = w ^ 4;
    float lt = 0.f;

    #pragma unroll
    for (int ct = 0; ct < 2; ++ct) {         // FULL unroll: static acc[ct]
        __syncthreads();
        #pragma unroll
        for (int r = 0; r < 16; ++r) comb[w][lane][r] = acc[ct][r];
        if (ct == 0) comb[w][lane][16] = l;
        __syncthreads();
        if (ct == 0) lt = l + comb[pw][lane][16];
        if (jq == ct) {                      // jq=0 writes ct0, jq=1 writes ct1
            const float sc = gam / lt;
            #pragma unroll
            for (int r = 0; r < 16; ++r) {
                const float o = acc[ct][r] + comb[pw][lane][r];
                const int c = ci * 64 + ct * 32 + (r & 3) + 8 * (r >> 2) + 4 * h;
                const size_t idx = ((size_t)(b * CCH + c)) * NPIX + i0 + il;
                out[idx] = x[idx] + o * sc;
            }
        }
    }
}

// ---------------------------------------------------------------------------
// Workspace (bf16 elems):
//   wbf[81920] | xfrag[4194304] | qfrag[524288] | kfrag[524288] | vfrag[4194304]
// = 9,519,104 elems = 19.1 MB.
// ---------------------------------------------------------------------------
extern "C" void kernel_launch(void* const* d_in, const int* in_sizes, int n_in,
                              void* d_out, int out_size, void* d_ws, size_t ws_size,
                              hipStream_t stream) {
    const float* x     = (const float*)d_in[0];
    const float* Wq    = (const float*)d_in[1];
    const float* bq    = (const float*)d_in[2];
    const float* Wk    = (const float*)d_in[3];
    const float* bk    = (const float*)d_in[4];
    const float* Wv    = (const float*)d_in[5];
    const float* bv    = (const float*)d_in[6];
    const float* gamma = (const float*)d_in[7];
    float* out = (float*)d_out;

    unsigned short* ws    = (unsigned short*)d_ws;
    unsigned short* wbf   = ws;
    unsigned short* xfrag = ws + 81920;
    unsigned short* qfrag = xfrag + (size_t)4194304;
    unsigned short* kfrag = qfrag + (size_t)524288;
    unsigned short* vfrag = kfrag + (size_t)524288;

    wconv_kernel<<<dim3(320), dim3(256), 0, stream>>>(Wq, Wk, Wv, wbf);
    xt_kernel<<<dim3(256), dim3(256), 0, stream>>>(x, xfrag);
    proj_kernel<<<dim3(256), dim3(320), 0, stream>>>(
        xfrag, wbf, bq, bk, bv, qfrag, kfrag, vfrag);
    attn_kernel<<<dim3(512), dim3(512), 0, stream>>>(
        qfrag, kfrag, vfrag, x, gamma, out);
}

// Round 8
// 150.712 us; speedup vs baseline: 1.3980x; 1.3980x over previous
//
#include <hip/hip_runtime.h>
#include <math.h>

// Problem constants (fixed by setup_inputs)
#define BATCH 4
#define CCH   256   // channels
#define DQK   32    // q/k channels
#define NPIX  4096  // H*W
#define LOG2E 1.44269504088896340736f

typedef __attribute__((ext_vector_type(8)))  short          short8_t;
typedef __attribute__((ext_vector_type(4)))  unsigned short ushort4_t;
typedef __attribute__((ext_vector_type(8)))  unsigned short ushort8_t;
typedef __attribute__((ext_vector_type(16))) float          f32x16;
typedef __attribute__((ext_vector_type(2)))  unsigned int   uint2_t;

#if __has_builtin(__builtin_amdgcn_exp2f)
#define EXP2F(x) __builtin_amdgcn_exp2f(x)
#else
#define EXP2F(x) exp2f(x)
#endif

#define MFMA32(a, b, c) __builtin_amdgcn_mfma_f32_32x32x16_bf16(a, b, c, 0, 0, 0)

static __device__ __forceinline__ unsigned short f2bf(float f) {
    union { float f; unsigned int u; } v; v.f = f;
    unsigned int r = v.u + 0x7FFFu + ((v.u >> 16) & 1u);   // RNE
    return (unsigned short)(r >> 16);
}

static __device__ __forceinline__ short8_t cat8(ushort4_t a, ushort4_t b) {
    ushort8_t c = __builtin_shufflevector(a, b, 0, 1, 2, 3, 4, 5, 6, 7);
    short8_t r; __builtin_memcpy(&r, &c, 16); return r;
}

static __device__ __forceinline__ short8_t u4_to_s8(const unsigned int* u) {
    short8_t r; __builtin_memcpy(&r, u, 16); return r;
}

// permlane32_swap(a,b) -> {x = {a_lo32lanes, b_lo32lanes}, y = {a_hi, b_hi}}
static __device__ __forceinline__ uint2_t plswap(unsigned int a, unsigned int b) {
#if __has_builtin(__builtin_amdgcn_permlane32_swap)
    return __builtin_amdgcn_permlane32_swap(a, b, false, false);
#else
    const unsigned int sa = (unsigned int)__shfl_xor((int)a, 32);
    const unsigned int sb = (unsigned int)__shfl_xor((int)b, 32);
    const int h = (threadIdx.x >> 5) & 1;
    uint2_t r;
    r.x = h ? sb : a;
    r.y = h ? b : sa;
    return r;
#endif
}

// S (C-layout) -> exp2 -> packed bf16 PV B-operand fragments; accumulates l
static __device__ __forceinline__ void make_bfrag(
    const f32x16& s, float& l0, float& l1, unsigned int bfr[2][4])
{
    float pv[16];
    #pragma unroll
    for (int r = 0; r < 16; ++r) pv[r] = EXP2F(s[r]);
    #pragma unroll
    for (int r = 0; r < 16; r += 2) { l0 += pv[r]; l1 += pv[r + 1]; }
    unsigned int P[8];
    #pragma unroll
    for (int v = 0; v < 8; ++v)
        P[v] = __builtin_amdgcn_perm(__float_as_uint(pv[2 * v + 1]),
                                     __float_as_uint(pv[2 * v]), 0x07060302u);
    #pragma unroll
    for (int kp = 0; kp < 2; ++kp) {
        const uint2_t r02 = plswap(P[4 * kp + 0], P[4 * kp + 2]);
        const uint2_t r13 = plswap(P[4 * kp + 1], P[4 * kp + 3]);
        bfr[kp][0] = r02.x; bfr[kp][1] = r13.x;
        bfr[kp][2] = r02.y; bfr[kp][3] = r13.y;
    }
}

// ---------------------------------------------------------------------------
// Stage 0a: weights -> bf16 A-fragment layout wbf[((c>>3)*320 + o)*8 + (c&7)]
// (o: 0-31 Wq x log2e, 32-63 Wk, 64-319 Wv).
// ---------------------------------------------------------------------------
__global__ __launch_bounds__(256) void wconv_kernel(
    const float* __restrict__ Wq, const float* __restrict__ Wk,
    const float* __restrict__ Wv, unsigned short* __restrict__ wbf)
{
    const int idx = blockIdx.x * 256 + threadIdx.x;   // grid 320 -> 81920
    const int o = idx >> 8, c = idx & 255;
    float v;
    if (o < 32)      v = Wq[o * 256 + c] * LOG2E;
    else if (o < 64) v = Wk[(o - 32) * 256 + c];
    else             v = Wv[(o - 64) * 256 + c];
    wbf[((c >> 3) * 320 + o) * 8 + (c & 7)] = f2bf(v);
}

// ---------------------------------------------------------------------------
// Stage 0b: x (fp32 [b][c][n]) -> bf16 B-fragment layout
//   xfrag[(((b*128 + nt)*32 + slot)*32 + il)*8 + e],  c = slot*8+e, n = nt*32+il
// Register-only transpose: block = (b, cg in 4, ng in 16) covers 64c x 256n.
// Reads: 256B bursts; writes: dense coalesced 16B/lane runs.
// ---------------------------------------------------------------------------
__global__ __launch_bounds__(256) void xt_kernel(
    const float* __restrict__ x, unsigned short* __restrict__ xfrag)
{
    const int b  = blockIdx.x >> 6;
    const int cg = (blockIdx.x >> 4) & 3;
    const int ng = blockIdx.x & 15;
    const int t  = threadIdx.x;
    const int w = t >> 6, l = t & 63;

    #pragma unroll
    for (int sgl = 0; sgl < 2; ++sgl) {
        const int sg = w * 2 + sgl;          // block-local c-octet, 0..7
        float f[4][8];
        #pragma unroll
        for (int p = 0; p < 8; ++p) {
            const float* row = x + ((size_t)(b * CCH + cg * 64 + sg * 8 + p)) * NPIX
                                 + ng * 256;
            #pragma unroll
            for (int j = 0; j < 4; ++j)
                f[j][p] = row[j * 64 + l];
        }
        #pragma unroll
        for (int j = 0; j < 4; ++j) {
            unsigned int d[4];
            #pragma unroll
            for (int k = 0; k < 4; ++k)
                d[k] = __builtin_amdgcn_perm(__float_as_uint(f[j][2 * k + 1]),
                                             __float_as_uint(f[j][2 * k]), 0x07060302u);
            const int nt = ng * 8 + j * 2 + (l >> 5);
            unsigned short* dst = xfrag +
                ((((size_t)(b * 128 + nt) * 32) + cg * 8 + sg) * 32 + (l & 31)) * 8;
            *(short8_t*)dst = u4_to_s8(d);
        }
    }
}

// ---------------------------------------------------------------------------
// Stage 1: LDS-free MFMA projections. D[o=320][n] = W[o][c] * x[c][n].
// Block = (b, 64-n tile), grid 256, 320 thr = 5 waves (wave w: o = 64w..).
// K-loop: W A-frags + xfrag B-frags, all coalesced global loads, no barriers.
// Epilogue: per-wave LDS transpose (no barriers) into fragment layouts:
//   qfrag/kfrag[(((b*128+jt)*4 + dslot)*32 + n&31)*8]   (8 d-elems per chunk)
//   vfrag[(((b*128+jt)*4 + jslot)*256 + c)*8]           (8 j-elems per chunk)
// ---------------------------------------------------------------------------
__global__ __launch_bounds__(320) void proj_kernel(
    const unsigned short* __restrict__ xfrag, const unsigned short* __restrict__ wbf,
    const float* __restrict__ bq, const float* __restrict__ bk,
    const float* __restrict__ bv,
    unsigned short* __restrict__ qfrag, unsigned short* __restrict__ kfrag,
    unsigned short* __restrict__ vfrag)
{
    __shared__ unsigned short qkb[2 * 2 * 32 * 40];  // [it][q/k][n 32][d 32+pad]
    __shared__ unsigned short vbuf[4 * 64 * 72];     // per v-wave [c 64][n 64+pad]

    const int b   = blockIdx.x >> 6;
    const int nt0 = (blockIdx.x & 63) << 1;          // first 32-n tile of this block
    const int t   = threadIdx.x;
    const int w = t >> 6, lane = t & 63, il = lane & 31, h = lane >> 5;

    // bias prefetch (lane needs base + 8g + 4h + 0..3 for g = r>>2)
    float4 bA[4], bB[4];
    #pragma unroll
    for (int g = 0; g < 4; ++g) {
        if (w == 0) {
            bA[g] = *(const float4*)&bq[8 * g + 4 * h];
            bB[g] = *(const float4*)&bk[8 * g + 4 * h];
        } else {
            bA[g] = *(const float4*)&bv[(w - 1) * 64 + 8 * g + 4 * h];
            bB[g] = *(const float4*)&bv[(w - 1) * 64 + 32 + 8 * g + 4 * h];
        }
    }

    f32x16 acc[2][2];   // [o-half][it]
    #pragma unroll
    for (int a = 0; a < 2; ++a)
        #pragma unroll
        for (int i = 0; i < 2; ++i)
            #pragma unroll
            for (int r = 0; r < 16; ++r) acc[a][i][r] = 0.f;

    const unsigned short* wp = wbf + ((size_t)(h * 320 + w * 64 + il)) * 8;
    const unsigned short* xp0 = xfrag + (((size_t)(b * 128 + nt0) * 32 + h) * 32 + il) * 8;
    const unsigned short* xp1 = xp0 + (size_t)32 * 32 * 8;   // nt0+1

    #pragma unroll 4
    for (int ks = 0; ks < 16; ++ks) {
        const short8_t af0 = *(const short8_t*)(wp + ks * 5120);
        const short8_t af1 = *(const short8_t*)(wp + ks * 5120 + 256);
        const short8_t bf0 = *(const short8_t*)(xp0 + (size_t)ks * 2 * 256);
        const short8_t bf1 = *(const short8_t*)(xp1 + (size_t)ks * 2 * 256);
        acc[0][0] = MFMA32(af0, bf0, acc[0][0]);
        acc[0][1] = MFMA32(af0, bf1, acc[0][1]);
        acc[1][0] = MFMA32(af1, bf0, acc[1][0]);
        acc[1][1] = MFMA32(af1, bf1, acc[1][1]);
    }

    // ---- epilogue (same-wave LDS transposes only; zero barriers) ----
    if (w == 0) {
        // q = acc[0][it], k = acc[1][it].  C: col=il=n, row d = (r&3)+8*(r>>2)+4h
        #pragma unroll
        for (int it = 0; it < 2; ++it)
            #pragma unroll
            for (int r = 0; r < 16; ++r) {
                const int d = (r & 3) + 8 * (r >> 2) + 4 * h;
                qkb[(it * 2 + 0) * 1280 + il * 40 + d] =
                    f2bf(acc[0][it][r] + bA[r >> 2][r & 3] * LOG2E);
                qkb[(it * 2 + 1) * 1280 + il * 40 + d] =
                    f2bf(acc[1][it][r] + bB[r >> 2][r & 3]);
            }
        #pragma unroll
        for (int it = 0; it < 2; ++it)
            #pragma unroll
            for (int rep = 0; rep < 2; ++rep) {
                const int u = rep * 64 + lane;       // 128 chunks: slot(4) x n(32)
                const int slot = u >> 5, n = u & 31;
                ushort4_t qlo = *(const ushort4_t*)&qkb[(it * 2) * 1280 + n * 40 + slot * 8];
                ushort4_t qhi = *(const ushort4_t*)&qkb[(it * 2) * 1280 + n * 40 + slot * 8 + 4];
                ushort4_t klo = *(const ushort4_t*)&qkb[(it * 2 + 1) * 1280 + n * 40 + slot * 8];
                ushort4_t khi = *(const ushort4_t*)&qkb[(it * 2 + 1) * 1280 + n * 40 + slot * 8 + 4];
                const size_t o8 = (((size_t)(b * 128 + nt0 + it) * 4 + slot) * 32 + n) * 8;
                *(short8_t*)(qfrag + o8) = cat8(qlo, qhi);
                *(short8_t*)(kfrag + o8) = cat8(klo, khi);
            }
    } else {
        unsigned short* vb = vbuf + (w - 1) * 64 * 72;   // [c 64][n 64 pad 72]
        #pragma unroll
        for (int it = 0; it < 2; ++it)
            #pragma unroll
            for (int r = 0; r < 16; ++r) {
                const int orow = (r & 3) + 8 * (r >> 2) + 4 * h;
                vb[(orow)      * 72 + it * 32 + il] = f2bf(acc[0][it][r] + bA[r >> 2][r & 3]);
                vb[(orow + 32) * 72 + it * 32 + il] = f2bf(acc[1][it][r] + bB[r >> 2][r & 3]);
            }
        #pragma unroll
        for (int rep = 0; rep < 8; ++rep) {
            const int u = rep * 64 + lane;   // 512 chunks: (it,slot)(8) x c(64)
            const int c = u & 63, m = u >> 6;
            const int it = m >> 2, slot = m & 3;
            ushort4_t lo = *(const ushort4_t*)&vb[c * 72 + it * 32 + slot * 8];
            ushort4_t hi = *(const ushort4_t*)&vb[c * 72 + it * 32 + slot * 8 + 4];
            const size_t o8 = (((size_t)(b * 128 + nt0 + it) * 4 + slot) * 256 +
                               (w - 1) * 64 + c) * 8;
            *(short8_t*)(vfrag + o8) = cat8(lo, hi);
        }
    }
}

// ---------------------------------------------------------------------------
// Stage 2: MFMA flash attention — ZERO LDS / barriers in the main loop.
// v8 = round-3 champion (60.5us attn: grid 256, 64q blocks, 8 waves, wave =
// (it = w&1, ci = (w>>1)&1, jj = w>>2), acc[4], A/B chains, VGPR 108, no
// spill) + two within-wave stall fixes; occupancy stays 2 waves/SIMD
// (wave total approx. 108 arch + 64 agpr = 172 regs of the 512/SIMD pool --
// measured cap across rounds 4-7; every attempt to go past it lost more to
// spills/redundancy than occupancy gained).
// Fix 1 (S-pipeline): make_bfrag(s) consumes S computed ONE ITERATION ago;
// QK MFMAs for tile jt+2 issue right after, filling the matrix pipe while
// the VALU runs exp2/pack. Removes the QK-latency wait in front of every
// softmax (the dominant serial gap in round-3's 43% stall).
// Fix 2 (T5): s_setprio(1) around PV MFMA clusters -- barrier-free waves
// drift out of phase; priority keeps the MFMA-issuing wave fed (+4-7% attn
// in learn_hip m191).
// p = exp2(s) un-normalized => disjoint-j partials add linearly; LDS combine
// with partner w^4 at the end. Grid 256, XCD-batch affinity via blk%8.
// ---------------------------------------------------------------------------
struct KStage { short8_t k0, k1; };

__global__ __launch_bounds__(512, 2) void attn_kernel(
    const unsigned short* __restrict__ qfrag,
    const unsigned short* __restrict__ kfrag,
    const unsigned short* __restrict__ vfrag,
    const float* __restrict__ x,             // [B][C][N] fp32
    const float* __restrict__ gamma,
    float* __restrict__ out)
{
    __shared__ float comb[8][64][17];        // 34.8 KB, end-combine only

    const int m8 = blockIdx.x & 7;
    const int b  = m8 >> 1;
    const int itile = ((blockIdx.x >> 3) << 1) | (m8 & 1);   // 0..63
    const int i0 = itile << 6;
    const int t  = threadIdx.x;
    const int w = t >> 6, lane = t & 63, il = lane & 31, h = lane >> 5;
    const int it = w & 1, ci = (w >> 1) & 1, jj = w >> 2;

    // Q fragments for this wave's single it: chunk (nt = itile*2+it, ks*2+h, il)
    short8_t qf[2];
    #pragma unroll
    for (int ks = 0; ks < 2; ++ks)
        qf[ks] = *(const short8_t*)(qfrag +
            (((size_t)(b * 128 + itile * 2 + it) * 4 + ks * 2 + h) * 32 + il) * 8);

    const size_t kbase = (size_t)(b * 128 + jj * 64) * 1024 + h * 256 + il * 8;
    const size_t vbase = (size_t)(b * 128 + jj * 64) * 8192 + h * 2048 +
                         (ci * 128 + il) * 8;

    f32x16 zf;
    #pragma unroll
    for (int r = 0; r < 16; ++r) zf[r] = 0.f;
    f32x16 acc[4];       // [ct]  (ct: 32-channel tiles at ci*128 + ct*32)
    #pragma unroll
    for (int c4 = 0; c4 < 4; ++c4) acc[c4] = zf;
    float ls[2] = {0.f, 0.f};

    KStage A, B;
    short8_t va[4][2], vb[4][2];   // [ct][kp], double-buffered j-tiles

    auto loadK = [&](KStage& S, int jt) {
        const unsigned short* kp = kfrag + kbase + (size_t)jt * 1024;
        S.k0 = *(const short8_t*)kp;
        S.k1 = *(const short8_t*)(kp + 512);
    };
    auto loadV = [&](short8_t (&vv)[4][2], int jt) {
        const unsigned short* vp = vfrag + vbase + (size_t)jt * 8192;
        #pragma unroll
        for (int ct = 0; ct < 4; ++ct) {
            vv[ct][0] = *(const short8_t*)(vp + ct * 256);
            vv[ct][1] = *(const short8_t*)(vp + ct * 256 + 4096);
        }
    };

    // ---- prologue: S for tiles 0,1 computed ahead; K for tiles 2,3 staged.
    loadK(A, 0);
    loadK(B, 1);
    f32x16 sA = MFMA32(A.k0, qf[0], zf);
    sA = MFMA32(A.k1, qf[1], sA);
    f32x16 sB = MFMA32(B.k0, qf[0], zf);
    sB = MFMA32(B.k1, qf[1], sB);
    loadK(A, 2);
    loadK(B, 3);
    loadV(va, 0);
    loadV(vb, 1);

    #pragma unroll 1
    for (int jt = 0; jt < 64; jt += 2) {
        // --- chain A: softmax(tile jt) from last iter's S; QK(jt+2); PV(jt)
        unsigned int bfA[2][4];
        make_bfrag(sA, ls[0], ls[1], bfA);
        sA = MFMA32(A.k0, qf[0], zf);        // S for tile jt+2 (phantom at end)
        sA = MFMA32(A.k1, qf[1], sA);
        if (jt + 4 < 64) loadK(A, jt + 4);
        __builtin_amdgcn_s_setprio(1);
        #pragma unroll
        for (int ct = 0; ct < 4; ++ct) {
            acc[ct] = MFMA32(va[ct][0], u4_to_s8(bfA[0]), acc[ct]);
            acc[ct] = MFMA32(va[ct][1], u4_to_s8(bfA[1]), acc[ct]);
        }
        __builtin_amdgcn_s_setprio(0);
        if (jt + 2 < 64) loadV(va, jt + 2);

        // --- chain B: same, one tile behind
        unsigned int bfB[2][4];
        make_bfrag(sB, ls[0], ls[1], bfB);
        sB = MFMA32(B.k0, qf[0], zf);        // S for tile jt+3
        sB = MFMA32(B.k1, qf[1], sB);
        if (jt + 5 < 64) loadK(B, jt + 5);
        __builtin_amdgcn_s_setprio(1);
        #pragma unroll
        for (int ct = 0; ct < 4; ++ct) {
            acc[ct] = MFMA32(vb[ct][0], u4_to_s8(bfB[0]), acc[ct]);
            acc[ct] = MFMA32(vb[ct][1], u4_to_s8(bfB[1]), acc[ct]);
        }
        __builtin_amdgcn_s_setprio(0);
        if (jt + 3 < 64) loadV(vb, jt + 3);
    }

    // ---- combine j-halves (partner wave w^4, same it/ci) and write out ----
    float l = ls[0] + ls[1];
    l += __shfl_xor(l, 32);                  // combine h halves of j rows
    const float gam = gamma[0];
    const int pw = w ^ 4;
    float lt = 0.f;

    #pragma unroll
    for (int ct = 0; ct < 4; ++ct) {         // FULL unroll: static acc[ct]
        __syncthreads();
        #pragma unroll
        for (int r = 0; r < 16; ++r) comb[w][lane][r] = acc[ct][r];
        if (ct == 0) comb[w][lane][16] = l;
        __syncthreads();
        if (ct == 0) lt = l + comb[pw][lane][16];
        if ((ct >> 1) == jj) {               // jj=0 writes ct 0-1, jj=1 ct 2-3
            const float sc = gam / lt;
            #pragma unroll
            for (int r = 0; r < 16; ++r) {
                const float o = acc[ct][r] + comb[pw][lane][r];
                const int c = ci * 128 + ct * 32 + (r & 3) + 8 * (r >> 2) + 4 * h;
                const size_t idx = ((size_t)(b * CCH + c)) * NPIX + i0 +
                                   it * 32 + il;
                out[idx] = x[idx] + o * sc;
            }
        }
    }
}

// ---------------------------------------------------------------------------
// Workspace (bf16 elems):
//   wbf[81920] | xfrag[4194304] | qfrag[524288] | kfrag[524288] | vfrag[4194304]
// = 9,519,104 elems = 19.1 MB.
// ---------------------------------------------------------------------------
extern "C" void kernel_launch(void* const* d_in, const int* in_sizes, int n_in,
                              void* d_out, int out_size, void* d_ws, size_t ws_size,
                              hipStream_t stream) {
    const float* x     = (const float*)d_in[0];
    const float* Wq    = (const float*)d_in[1];
    const float* bq    = (const float*)d_in[2];
    const float* Wk    = (const float*)d_in[3];
    const float* bk    = (const float*)d_in[4];
    const float* Wv    = (const float*)d_in[5];
    const float* bv    = (const float*)d_in[6];
    const float* gamma = (const float*)d_in[7];
    float* out = (float*)d_out;

    unsigned short* ws    = (unsigned short*)d_ws;
    unsigned short* wbf   = ws;
    unsigned short* xfrag = ws + 81920;
    unsigned short* qfrag = xfrag + (size_t)4194304;
    unsigned short* kfrag = qfrag + (size_t)524288;
    unsigned short* vfrag = kfrag + (size_t)524288;

    wconv_kernel<<<dim3(320), dim3(256), 0, stream>>>(Wq, Wk, Wv, wbf);
    xt_kernel<<<dim3(256), dim3(256), 0, stream>>>(x, xfrag);
    proj_kernel<<<dim3(256), dim3(320), 0, stream>>>(
        xfrag, wbf, bq, bk, bv, qfrag, kfrag, vfrag);
    attn_kernel<<<dim3(256), dim3(512), 0, stream>>>(
        qfrag, kfrag, vfrag, x, gamma, out);
}

// Round 9
// 146.708 us; speedup vs baseline: 1.4362x; 1.0273x over previous
//
#include <hip/hip_runtime.h>
#include <math.h>

// Problem constants (fixed by setup_inputs)
#define BATCH 4
#define CCH   256   // channels
#define DQK   32    // q/k channels
#define NPIX  4096  // H*W
#define LOG2E 1.44269504088896340736f

typedef __attribute__((ext_vector_type(8)))  short          short8_t;
typedef __attribute__((ext_vector_type(4)))  unsigned short ushort4_t;
typedef __attribute__((ext_vector_type(8)))  unsigned short ushort8_t;
typedef __attribute__((ext_vector_type(16))) float          f32x16;
typedef __attribute__((ext_vector_type(2)))  unsigned int   uint2_t;

#if __has_builtin(__builtin_amdgcn_exp2f)
#define EXP2F(x) __builtin_amdgcn_exp2f(x)
#else
#define EXP2F(x) exp2f(x)
#endif

#define MFMA32(a, b, c) __builtin_amdgcn_mfma_f32_32x32x16_bf16(a, b, c, 0, 0, 0)

static __device__ __forceinline__ unsigned short f2bf(float f) {
    union { float f; unsigned int u; } v; v.f = f;
    unsigned int r = v.u + 0x7FFFu + ((v.u >> 16) & 1u);   // RNE
    return (unsigned short)(r >> 16);
}

static __device__ __forceinline__ short8_t cat8(ushort4_t a, ushort4_t b) {
    ushort8_t c = __builtin_shufflevector(a, b, 0, 1, 2, 3, 4, 5, 6, 7);
    short8_t r; __builtin_memcpy(&r, &c, 16); return r;
}

static __device__ __forceinline__ short8_t u4_to_s8(const unsigned int* u) {
    short8_t r; __builtin_memcpy(&r, u, 16); return r;
}

// permlane32_swap(a,b) -> {x = {a_lo32lanes, b_lo32lanes}, y = {a_hi, b_hi}}
static __device__ __forceinline__ uint2_t plswap(unsigned int a, unsigned int b) {
#if __has_builtin(__builtin_amdgcn_permlane32_swap)
    return __builtin_amdgcn_permlane32_swap(a, b, false, false);
#else
    const unsigned int sa = (unsigned int)__shfl_xor((int)a, 32);
    const unsigned int sb = (unsigned int)__shfl_xor((int)b, 32);
    const int h = (threadIdx.x >> 5) & 1;
    uint2_t r;
    r.x = h ? sb : a;
    r.y = h ? b : sa;
    return r;
#endif
}

// S (C-layout) -> exp2 -> packed bf16 PV B-operand fragments; accumulates l
static __device__ __forceinline__ void make_bfrag(
    const f32x16& s, float& l0, float& l1, unsigned int bfr[2][4])
{
    float pv[16];
    #pragma unroll
    for (int r = 0; r < 16; ++r) pv[r] = EXP2F(s[r]);
    #pragma unroll
    for (int r = 0; r < 16; r += 2) { l0 += pv[r]; l1 += pv[r + 1]; }
    unsigned int P[8];
    #pragma unroll
    for (int v = 0; v < 8; ++v)
        P[v] = __builtin_amdgcn_perm(__float_as_uint(pv[2 * v + 1]),
                                     __float_as_uint(pv[2 * v]), 0x07060302u);
    #pragma unroll
    for (int kp = 0; kp < 2; ++kp) {
        const uint2_t r02 = plswap(P[4 * kp + 0], P[4 * kp + 2]);
        const uint2_t r13 = plswap(P[4 * kp + 1], P[4 * kp + 3]);
        bfr[kp][0] = r02.x; bfr[kp][1] = r13.x;
        bfr[kp][2] = r02.y; bfr[kp][3] = r13.y;
    }
}

// ---------------------------------------------------------------------------
// Stage 0: weights -> bf16 A-fragment layout wbf[((c>>3)*320 + o)*8 + (c&7)]
// (o: 0-31 Wq x log2e, 32-63 Wk, 64-319 Wv).
// ---------------------------------------------------------------------------
__global__ __launch_bounds__(256) void wconv_kernel(
    const float* __restrict__ Wq, const float* __restrict__ Wk,
    const float* __restrict__ Wv, unsigned short* __restrict__ wbf)
{
    const int idx = blockIdx.x * 256 + threadIdx.x;   // grid 320 -> 81920
    const int o = idx >> 8, c = idx & 255;
    float v;
    if (o < 32)      v = Wq[o * 256 + c] * LOG2E;
    else if (o < 64) v = Wk[(o - 32) * 256 + c];
    else             v = Wv[(o - 64) * 256 + c];
    wbf[((c >> 3) * 320 + o) * 8 + (c & 7)] = f2bf(v);
}

// ---------------------------------------------------------------------------
// Stage 1 (v9 FUSED xt+proj): one kernel does x->bf16 B-frag transpose into
// LDS, then the MFMA projections, then the fragment-layout epilogue.
// Rationale: rounds 0-8 consistently show total - attn ~= 85-90us while
// first-principles prep cost is ~7-10us; the old path paid an extra launch
// boundary + an 8MB xfrag HBM write + 8MB re-read. A proj block's B slice
// (256c x 64n) is exactly what its own transpose needs -> block-local LDS
// transpose removes the cross-block dependency that forced the split.
// Block = (b, 64-n tile), grid 256, 320 thr = 5 waves.
// Phase 1: float4 loads of x (coalesced 256B row-segments), f2bf, LDS store
//   in B-frag layout xls[ntl][slot=c>>3][il=n&31][e=c&7]  (32 KB).
// Phase 2: K-loop, W A-frags from global (L2-hot), B-frags via ds_read_b128
//   (lanes stride 16B; h-halves alias 2-way = free). Zero extra barriers.
// Phase 3: per-wave LDS-transpose epilogue (unchanged from v8):
//   qfrag/kfrag[(((b*128+jt)*4 + dslot)*32 + n&31)*8]
//   vfrag[(((b*128+jt)*4 + jslot)*256 + c)*8]
// LDS: 32 + 10 + 36.8 = 78.8 KB, 1 block/CU.
// ---------------------------------------------------------------------------
__global__ __launch_bounds__(320) void xtproj_kernel(
    const float* __restrict__ x, const unsigned short* __restrict__ wbf,
    const float* __restrict__ bq, const float* __restrict__ bk,
    const float* __restrict__ bv,
    unsigned short* __restrict__ qfrag, unsigned short* __restrict__ kfrag,
    unsigned short* __restrict__ vfrag)
{
    __shared__ unsigned short xls[2][32][32][8];     // 32 KB B-frag staging
    __shared__ unsigned short qkb[2 * 2 * 32 * 40];  // [it][q/k][n 32][d 32+pad]
    __shared__ unsigned short vbuf[4 * 64 * 72];     // per v-wave [c 64][n 64+pad]

    const int b   = blockIdx.x >> 6;
    const int nt0 = (blockIdx.x & 63) << 1;          // first 32-n tile of this block
    const int n0  = nt0 << 5;                        // 64-aligned pixel base
    const int t   = threadIdx.x;
    const int w = t >> 6, lane = t & 63, il = lane & 31, h = lane >> 5;

    // ---- phase 1: x[b][c][n0..n0+63] -> LDS B-frag layout (float4 loads) ----
    for (int q = t; q < 4096; q += 320) {            // 4096 quads = 256c x 16
        const int c  = q >> 4;
        const int n4 = (q & 15) << 2;                // 0..60, never crosses 32
        const float4 f = *(const float4*)&x[((size_t)(b * CCH + c)) * NPIX + n0 + n4];
        unsigned short* dst = &xls[n4 >> 5][c >> 3][n4 & 31][c & 7];
        dst[0]  = f2bf(f.x);                         // il stride = 8 shorts
        dst[8]  = f2bf(f.y);
        dst[16] = f2bf(f.z);
        dst[24] = f2bf(f.w);
    }

    // bias prefetch (lane needs base + 8g + 4h + 0..3 for g = r>>2)
    float4 bA[4], bB[4];
    #pragma unroll
    for (int g = 0; g < 4; ++g) {
        if (w == 0) {
            bA[g] = *(const float4*)&bq[8 * g + 4 * h];
            bB[g] = *(const float4*)&bk[8 * g + 4 * h];
        } else {
            bA[g] = *(const float4*)&bv[(w - 1) * 64 + 8 * g + 4 * h];
            bB[g] = *(const float4*)&bv[(w - 1) * 64 + 32 + 8 * g + 4 * h];
        }
    }

    f32x16 acc[2][2];   // [o-half][it]
    #pragma unroll
    for (int a = 0; a < 2; ++a)
        #pragma unroll
        for (int i = 0; i < 2; ++i)
            #pragma unroll
            for (int r = 0; r < 16; ++r) acc[a][i][r] = 0.f;

    __syncthreads();                                 // xls ready

    // ---- phase 2: K-loop (W from global, B-frags from LDS) ----
    const unsigned short* wp = wbf + ((size_t)(h * 320 + w * 64 + il)) * 8;

    #pragma unroll 4
    for (int ks = 0; ks < 16; ++ks) {
        const short8_t af0 = *(const short8_t*)(wp + ks * 5120);
        const short8_t af1 = *(const short8_t*)(wp + ks * 5120 + 256);
        const short8_t bf0 = *(const short8_t*)&xls[0][2 * ks + h][il][0];
        const short8_t bf1 = *(const short8_t*)&xls[1][2 * ks + h][il][0];
        acc[0][0] = MFMA32(af0, bf0, acc[0][0]);
        acc[0][1] = MFMA32(af0, bf1, acc[0][1]);
        acc[1][0] = MFMA32(af1, bf0, acc[1][0]);
        acc[1][1] = MFMA32(af1, bf1, acc[1][1]);
    }

    // ---- phase 3: epilogue (same-wave LDS transposes only; no barriers) ----
    if (w == 0) {
        // q = acc[0][it], k = acc[1][it].  C: col=il=n, row d = (r&3)+8*(r>>2)+4h
        #pragma unroll
        for (int it = 0; it < 2; ++it)
            #pragma unroll
            for (int r = 0; r < 16; ++r) {
                const int d = (r & 3) + 8 * (r >> 2) + 4 * h;
                qkb[(it * 2 + 0) * 1280 + il * 40 + d] =
                    f2bf(acc[0][it][r] + bA[r >> 2][r & 3] * LOG2E);
                qkb[(it * 2 + 1) * 1280 + il * 40 + d] =
                    f2bf(acc[1][it][r] + bB[r >> 2][r & 3]);
            }
        #pragma unroll
        for (int it = 0; it < 2; ++it)
            #pragma unroll
            for (int rep = 0; rep < 2; ++rep) {
                const int u = rep * 64 + lane;       // 128 chunks: slot(4) x n(32)
                const int slot = u >> 5, n = u & 31;
                ushort4_t qlo = *(const ushort4_t*)&qkb[(it * 2) * 1280 + n * 40 + slot * 8];
                ushort4_t qhi = *(const ushort4_t*)&qkb[(it * 2) * 1280 + n * 40 + slot * 8 + 4];
                ushort4_t klo = *(const ushort4_t*)&qkb[(it * 2 + 1) * 1280 + n * 40 + slot * 8];
                ushort4_t khi = *(const ushort4_t*)&qkb[(it * 2 + 1) * 1280 + n * 40 + slot * 8 + 4];
                const size_t o8 = (((size_t)(b * 128 + nt0 + it) * 4 + slot) * 32 + n) * 8;
                *(short8_t*)(qfrag + o8) = cat8(qlo, qhi);
                *(short8_t*)(kfrag + o8) = cat8(klo, khi);
            }
    } else {
        unsigned short* vb = vbuf + (w - 1) * 64 * 72;   // [c 64][n 64 pad 72]
        #pragma unroll
        for (int it = 0; it < 2; ++it)
            #pragma unroll
            for (int r = 0; r < 16; ++r) {
                const int orow = (r & 3) + 8 * (r >> 2) + 4 * h;
                vb[(orow)      * 72 + it * 32 + il] = f2bf(acc[0][it][r] + bA[r >> 2][r & 3]);
                vb[(orow + 32) * 72 + it * 32 + il] = f2bf(acc[1][it][r] + bB[r >> 2][r & 3]);
            }
        #pragma unroll
        for (int rep = 0; rep < 8; ++rep) {
            const int u = rep * 64 + lane;   // 512 chunks: (it,slot)(8) x c(64)
            const int c = u & 63, m = u >> 6;
            const int it = m >> 2, slot = m & 3;
            ushort4_t lo = *(const ushort4_t*)&vb[c * 72 + it * 32 + slot * 8];
            ushort4_t hi = *(const ushort4_t*)&vb[c * 72 + it * 32 + slot * 8 + 4];
            const size_t o8 = (((size_t)(b * 128 + nt0 + it) * 4 + slot) * 256 +
                               (w - 1) * 64 + c) * 8;
            *(short8_t*)(vfrag + o8) = cat8(lo, hi);
        }
    }
}

// ---------------------------------------------------------------------------
// Stage 2: MFMA flash attention — ZERO LDS / barriers in the main loop.
// Unchanged from round 8 (61.5us, VGPR 120, no spill; = round-3 plateau).
// Occupancy is structurally 2 waves/SIMD (~108 arch + 64 agpr = 172 of the
// 512/SIMD pool); rounds 4-7 proved shrinking below that costs more in
// spills/redundancy than occupancy buys.
// ---------------------------------------------------------------------------
struct KStage { short8_t k0, k1; };

__global__ __launch_bounds__(512, 2) void attn_kernel(
    const unsigned short* __restrict__ qfrag,
    const unsigned short* __restrict__ kfrag,
    const unsigned short* __restrict__ vfrag,
    const float* __restrict__ x,             // [B][C][N] fp32
    const float* __restrict__ gamma,
    float* __restrict__ out)
{
    __shared__ float comb[8][64][17];        // 34.8 KB, end-combine only

    const int m8 = blockIdx.x & 7;
    const int b  = m8 >> 1;
    const int itile = ((blockIdx.x >> 3) << 1) | (m8 & 1);   // 0..63
    const int i0 = itile << 6;
    const int t  = threadIdx.x;
    const int w = t >> 6, lane = t & 63, il = lane & 31, h = lane >> 5;
    const int it = w & 1, ci = (w >> 1) & 1, jj = w >> 2;

    // Q fragments for this wave's single it: chunk (nt = itile*2+it, ks*2+h, il)
    short8_t qf[2];
    #pragma unroll
    for (int ks = 0; ks < 2; ++ks)
        qf[ks] = *(const short8_t*)(qfrag +
            (((size_t)(b * 128 + itile * 2 + it) * 4 + ks * 2 + h) * 32 + il) * 8);

    const size_t kbase = (size_t)(b * 128 + jj * 64) * 1024 + h * 256 + il * 8;
    const size_t vbase = (size_t)(b * 128 + jj * 64) * 8192 + h * 2048 +
                         (ci * 128 + il) * 8;

    f32x16 zf;
    #pragma unroll
    for (int r = 0; r < 16; ++r) zf[r] = 0.f;
    f32x16 acc[4];       // [ct]  (ct: 32-channel tiles at ci*128 + ct*32)
    #pragma unroll
    for (int c4 = 0; c4 < 4; ++c4) acc[c4] = zf;
    float ls[2] = {0.f, 0.f};

    KStage A, B;
    short8_t va[4][2], vb[4][2];   // [ct][kp], double-buffered j-tiles

    auto loadK = [&](KStage& S, int jt) {
        const unsigned short* kp = kfrag + kbase + (size_t)jt * 1024;
        S.k0 = *(const short8_t*)kp;
        S.k1 = *(const short8_t*)(kp + 512);
    };
    auto loadV = [&](short8_t (&vv)[4][2], int jt) {
        const unsigned short* vp = vfrag + vbase + (size_t)jt * 8192;
        #pragma unroll
        for (int ct = 0; ct < 4; ++ct) {
            vv[ct][0] = *(const short8_t*)(vp + ct * 256);
            vv[ct][1] = *(const short8_t*)(vp + ct * 256 + 4096);
        }
    };

    // ---- prologue: S for tiles 0,1 computed ahead; K for tiles 2,3 staged.
    loadK(A, 0);
    loadK(B, 1);
    f32x16 sA = MFMA32(A.k0, qf[0], zf);
    sA = MFMA32(A.k1, qf[1], sA);
    f32x16 sB = MFMA32(B.k0, qf[0], zf);
    sB = MFMA32(B.k1, qf[1], sB);
    loadK(A, 2);
    loadK(B, 3);
    loadV(va, 0);
    loadV(vb, 1);

    #pragma unroll 1
    for (int jt = 0; jt < 64; jt += 2) {
        // --- chain A: softmax(tile jt) from last iter's S; QK(jt+2); PV(jt)
        unsigned int bfA[2][4];
        make_bfrag(sA, ls[0], ls[1], bfA);
        sA = MFMA32(A.k0, qf[0], zf);        // S for tile jt+2 (phantom at end)
        sA = MFMA32(A.k1, qf[1], sA);
        if (jt + 4 < 64) loadK(A, jt + 4);
        __builtin_amdgcn_s_setprio(1);
        #pragma unroll
        for (int ct = 0; ct < 4; ++ct) {
            acc[ct] = MFMA32(va[ct][0], u4_to_s8(bfA[0]), acc[ct]);
            acc[ct] = MFMA32(va[ct][1], u4_to_s8(bfA[1]), acc[ct]);
        }
        __builtin_amdgcn_s_setprio(0);
        if (jt + 2 < 64) loadV(va, jt + 2);

        // --- chain B: same, one tile behind
        unsigned int bfB[2][4];
        make_bfrag(sB, ls[0], ls[1], bfB);
        sB = MFMA32(B.k0, qf[0], zf);        // S for tile jt+3
        sB = MFMA32(B.k1, qf[1], sB);
        if (jt + 5 < 64) loadK(B, jt + 5);
        __builtin_amdgcn_s_setprio(1);
        #pragma unroll
        for (int ct = 0; ct < 4; ++ct) {
            acc[ct] = MFMA32(vb[ct][0], u4_to_s8(bfB[0]), acc[ct]);
            acc[ct] = MFMA32(vb[ct][1], u4_to_s8(bfB[1]), acc[ct]);
        }
        __builtin_amdgcn_s_setprio(0);
        if (jt + 3 < 64) loadV(vb, jt + 3);
    }

    // ---- combine j-halves (partner wave w^4, same it/ci) and write out ----
    float l = ls[0] + ls[1];
    l += __shfl_xor(l, 32);                  // combine h halves of j rows
    const float gam = gamma[0];
    const int pw = w ^ 4;
    float lt = 0.f;

    #pragma unroll
    for (int ct = 0; ct < 4; ++ct) {         // FULL unroll: static acc[ct]
        __syncthreads();
        #pragma unroll
        for (int r = 0; r < 16; ++r) comb[w][lane][r] = acc[ct][r];
        if (ct == 0) comb[w][lane][16] = l;
        __syncthreads();
        if (ct == 0) lt = l + comb[pw][lane][16];
        if ((ct >> 1) == jj) {               // jj=0 writes ct 0-1, jj=1 ct 2-3
            const float sc = gam / lt;
            #pragma unroll
            for (int r = 0; r < 16; ++r) {
                const float o = acc[ct][r] + comb[pw][lane][r];
                const int c = ci * 128 + ct * 32 + (r & 3) + 8 * (r >> 2) + 4 * h;
                const size_t idx = ((size_t)(b * CCH + c)) * NPIX + i0 +
                                   it * 32 + il;
                out[idx] = x[idx] + o * sc;
            }
        }
    }
}

// ---------------------------------------------------------------------------
// Workspace (bf16 elems):
//   wbf[81920] | qfrag[524288] | kfrag[524288] | vfrag[4194304]
// = 5,324,800 elems = 10.6 MB.  (xfrag eliminated by the xt+proj fusion.)
// ---------------------------------------------------------------------------
extern "C" void kernel_launch(void* const* d_in, const int* in_sizes, int n_in,
                              void* d_out, int out_size, void* d_ws, size_t ws_size,
                              hipStream_t stream) {
    const float* x     = (const float*)d_in[0];
    const float* Wq    = (const float*)d_in[1];
    const float* bq    = (const float*)d_in[2];
    const float* Wk    = (const float*)d_in[3];
    const float* bk    = (const float*)d_in[4];
    const float* Wv    = (const float*)d_in[5];
    const float* bv    = (const float*)d_in[6];
    const float* gamma = (const float*)d_in[7];
    float* out = (float*)d_out;

    unsigned short* ws    = (unsigned short*)d_ws;
    unsigned short* wbf   = ws;
    unsigned short* qfrag = ws + 81920;
    unsigned short* kfrag = qfrag + (size_t)524288;
    unsigned short* vfrag = kfrag + (size_t)524288;

    wconv_kernel<<<dim3(320), dim3(256), 0, stream>>>(Wq, Wk, Wv, wbf);
    xtproj_kernel<<<dim3(256), dim3(320), 0, stream>>>(
        x, wbf, bq, bk, bv, qfrag, kfrag, vfrag);
    attn_kernel<<<dim3(256), dim3(512), 0, stream>>>(
        qfrag, kfrag, vfrag, x, gamma, out);
}